// Round 7
// baseline (276.960 us; speedup 1.0000x reference)
//
#include <hip/hip_runtime.h>
#include <math.h>

// Problem constants (from reference): T=131072, D_IN=1024, NE=64, top_k=2
constexpr int T_TOKENS = 131072;
constexpr int D        = 1024;
constexpr int NEXP     = 64;

constexpr int BM = 64;   // tokens per block
constexpr int BK = 64;   // K-slice staged in LDS per step
constexpr int NTHREADS = 256;

// Replicates np ref = OpenBLAS sgemm, SKYLAKEX target (Zen4/5 host, AVX512,
// DYNAMIC_ARCH routes Zen->gotoblas_SKYLAKEX). SGEMM_DEFAULT_Q = 320, and the
// level3 driver's K-split rule (take Q while rem>=2Q; halve when Q<rem<2Q)
// gives K=1024 -> panels 320+320+192+192. Per (t,e): each panel is a single
// ascending-k fp32 FMA chain from 0; C folded sequentially (beta=0 first):
//   logit = (((P1 + P2) + P3) + P4), each fold rounded separately.
// Fold boundaries: k = 320, 640, 832, 1024.
// Thread (ty=tid>>4, tx=tid&15): 4 tokens (m0=ty*4) x 4 experts (n0=tx*4).
__global__ __launch_bounds__(NTHREADS, 2)
void topk_router_kernel(const float* __restrict__ x,
                        const float* __restrict__ W,
                        float* __restrict__ out)
{
    __shared__ float Xs[BK][BM];    // [k][token]  (transposed on store)
    __shared__ float Ws[BK][NEXP];  // [k][expert]

    const int tid = threadIdx.x;
    const long t0 = (long)blockIdx.x * BM;

    const int tx = tid & 15;
    const int ty = tid >> 4;
    const int m0 = ty * 4;
    const int n0 = tx * 4;

    float accP[4][4];   // current-panel accumulator (FMA chain)
    float accT[4][4];   // folded total: (((P1+P2)+P3)+P4)
#pragma unroll
    for (int i = 0; i < 4; ++i)
#pragma unroll
        for (int j = 0; j < 4; ++j) { accP[i][j] = 0.0f; accT[i][j] = 0.0f; }

    // staging mapping: lane -> row (token/expert), wave -> k-chunk
    const int lt = tid & 63;   // token index / expert index within tile
    const int lc = tid >> 6;   // 0..3, covers k = lc*16 .. lc*16+15

    const float* xrow = x + (t0 + lt) * (long)D;
    const float* wrow = W + (long)lt * D;

    for (int k0 = 0; k0 < D; k0 += BK) {
#pragma unroll
        for (int u = 0; u < 4; ++u) {
            const int kk = lc * 16 + u * 4;
            float4 vx = *reinterpret_cast<const float4*>(xrow + k0 + kk);
            float4 vw = *reinterpret_cast<const float4*>(wrow + k0 + kk);
            Xs[kk + 0][lt] = vx.x;
            Xs[kk + 1][lt] = vx.y;
            Xs[kk + 2][lt] = vx.z;
            Xs[kk + 3][lt] = vx.w;
            Ws[kk + 0][lt] = vw.x;
            Ws[kk + 1][lt] = vw.y;
            Ws[kk + 2][lt] = vw.z;
            Ws[kk + 3][lt] = vw.w;
        }
        __syncthreads();

        // ascending k, one fp32 FMA per k per element (BLAS microkernel chain).
        // Panel boundaries (320, 640, 832) fall mid-tile (BK=64): process the
        // tile in two 32-element halves so folds happen at exact k.
#pragma unroll
        for (int half = 0; half < 2; ++half) {
#pragma unroll 8
            for (int kk = half * 32; kk < half * 32 + 32; ++kk) {
                float4 a = *reinterpret_cast<const float4*>(&Xs[kk][m0]);
                float4 b = *reinterpret_cast<const float4*>(&Ws[kk][n0]);
                const float af[4] = {a.x, a.y, a.z, a.w};
                const float bf[4] = {b.x, b.y, b.z, b.w};
#pragma unroll
                for (int i = 0; i < 4; ++i)
#pragma unroll
                    for (int j = 0; j < 4; ++j)
                        accP[i][j] = fmaf(af[i], bf[j], accP[i][j]);
            }
            const int kend = k0 + half * 32 + 32;
            // OpenBLAS SKYLAKEX K-split of 1024: 320 + 320 + 192 + 192
            if (kend == 320 || kend == 640 || kend == 832 || kend == 1024) {
#pragma unroll
                for (int i = 0; i < 4; ++i)
#pragma unroll
                    for (int j = 0; j < 4; ++j) {
                        accT[i][j] = __fadd_rn(accT[i][j], accP[i][j]);
                        accP[i][j] = 0.0f;
                    }
            }
        }
        __syncthreads();
    }

    // Epilogue: per-token top-2 over 64 experts (lower index wins ties).
    // Token m0+i's logits live in the 16 lanes sharing ty, 4 experts per lane.
#pragma unroll
    for (int i = 0; i < 4; ++i) {
        float v1 = accT[i][0]; int i1 = n0;
        float v2 = -INFINITY;  int i2 = 1 << 20;
#pragma unroll
        for (int j = 1; j < 4; ++j) {
            const float v = accT[i][j]; const int e = n0 + j;
            if (v > v1)      { v2 = v1; i2 = i1; v1 = v; i1 = e; }
            else if (v > v2) { v2 = v;  i2 = e; }
        }
        // merge across the 16-lane expert group (xor masks stay in-group)
#pragma unroll
        for (int m = 8; m >= 1; m >>= 1) {
            const float ov1 = __shfl_xor(v1, m);
            const int   oi1 = __shfl_xor(i1, m);
            const float ov2 = __shfl_xor(v2, m);
            const int   oi2 = __shfl_xor(i2, m);
            // tie-break: lower index wins on equal value
            const bool aw = (ov1 > v1) || (ov1 == v1 && oi1 < i1);
            const float nv1 = aw ? ov1 : v1; const int ni1 = aw ? oi1 : i1;
            const float c1v = aw ? v1  : ov1; const int c1i = aw ? i1  : oi1;
            const float c2v = aw ? ov2 : v2;  const int c2i = aw ? oi2 : i2;
            const bool bw = (c1v > c2v) || (c1v == c2v && c1i < c2i);
            v1 = nv1; i1 = ni1;
            v2 = bw ? c1v : c2v; i2 = bw ? c1i : c2i;
        }
        if (tx == 0) {
            const long t = t0 + m0 + i;
            const float e  = expf(v2 - v1);   // <= 1
            const float dn = 1.0f + e;
            out[t * 2 + 0] = (float)i1;       // indices stored as float values
            out[t * 2 + 1] = (float)i2;
            out[(long)T_TOKENS * 2 + t * 2 + 0] = 1.0f / dn;
            out[(long)T_TOKENS * 2 + t * 2 + 1] = e / dn;
        }
    }
}

extern "C" void kernel_launch(void* const* d_in, const int* in_sizes, int n_in,
                              void* d_out, int out_size, void* d_ws, size_t ws_size,
                              hipStream_t stream) {
    const float* x = (const float*)d_in[0];
    const float* W = (const float*)d_in[1];
    float* out = (float*)d_out;
    // d_in[2] is top_k (==2), fixed by the problem; k=2 is hardcoded.

    dim3 grid(T_TOKENS / BM);
    dim3 block(NTHREADS);
    topk_router_kernel<<<grid, block, 0, stream>>>(x, W, out);
}

// Round 8
// 260.574 us; speedup vs baseline: 1.0629x; 1.0629x over previous
//
#include <hip/hip_runtime.h>
#include <math.h>

// Problem constants (from reference): T=131072, D_IN=1024, NE=64, top_k=2
constexpr int T_TOKENS = 131072;
constexpr int D        = 1024;
constexpr int NEXP     = 64;

constexpr int BM = 256;  // tokens per block
constexpr int BK = 64;   // K-slice staged in LDS per step
constexpr int NTHREADS = 256;

// np ref = OpenBLAS sgemm, SKYLAKEX target (verified R7): K=1024 split into
// panels 320+320+192+192; per (t,e) each panel is a single ascending-k fp32
// FMA chain from 0; C folded sequentially: (((P1+P2)+P3)+P4), folds rounded
// separately at k = 320, 640, 832, 1024 (all multiples of BK=64).
//
// 8x8 register tile per thread: tx=tid&7 -> experts n0=tx*8..+7,
// ty=tid>>3 -> tokens m0=ty*8..+7. Per kk: 4 ds_read_b128 feed 64 FMAs
// (reads:FMA ratio halved vs R7's 4x4 tile -> LDS-issue bound 3.0x -> 1.5x).
__global__ __launch_bounds__(NTHREADS, 2)
void topk_router_kernel(const float* __restrict__ x,
                        const float* __restrict__ W,
                        float* __restrict__ out)
{
    __shared__ float Xs[BK][BM];    // [k][token] 64 KB (transposed on store)
    __shared__ float Ws[BK][NEXP];  // [k][expert] 16 KB

    const int tid = threadIdx.x;
    const long t0 = (long)blockIdx.x * BM;

    const int tx = tid & 7;
    const int ty = tid >> 3;
    const int n0 = tx * 8;
    const int m0 = ty * 8;

    float accP[8][8];   // current-panel accumulator (FMA chain)
    float accT[8][8];   // folded total
#pragma unroll
    for (int i = 0; i < 8; ++i)
#pragma unroll
        for (int j = 0; j < 8; ++j) { accP[i][j] = 0.0f; accT[i][j] = 0.0f; }

    // staging: x -> thread owns token column `tid`; W -> row tid&63, quarter tid>>6
    const float* xrow = x + (t0 + tid) * (long)D;
    const int wr = tid & 63;
    const int wc = tid >> 6;
    const float* wrow = W + (long)wr * D;

    for (int k0 = 0; k0 < D; k0 += BK) {
        // stage x tile (transpose to [k][t]; stride-1 lanes -> conflict-free writes)
#pragma unroll
        for (int c = 0; c < 4; ++c) {
            float4 v[4];
#pragma unroll
            for (int u = 0; u < 4; ++u)
                v[u] = *reinterpret_cast<const float4*>(xrow + k0 + c * 16 + u * 4);
#pragma unroll
            for (int u = 0; u < 4; ++u) {
                Xs[c * 16 + u * 4 + 0][tid] = v[u].x;
                Xs[c * 16 + u * 4 + 1][tid] = v[u].y;
                Xs[c * 16 + u * 4 + 2][tid] = v[u].z;
                Xs[c * 16 + u * 4 + 3][tid] = v[u].w;
            }
        }
        // stage W tile
#pragma unroll
        for (int u = 0; u < 4; ++u) {
            float4 vw = *reinterpret_cast<const float4*>(wrow + k0 + wc * 16 + u * 4);
            Ws[wc * 16 + u * 4 + 0][wr] = vw.x;
            Ws[wc * 16 + u * 4 + 1][wr] = vw.y;
            Ws[wc * 16 + u * 4 + 2][wr] = vw.z;
            Ws[wc * 16 + u * 4 + 3][wr] = vw.w;
        }
        __syncthreads();

        // ascending k, one fp32 FMA per k per element (BLAS microkernel chain)
#pragma unroll 4
        for (int kk = 0; kk < BK; ++kk) {
            float4 a0 = *reinterpret_cast<const float4*>(&Xs[kk][m0]);
            float4 a1 = *reinterpret_cast<const float4*>(&Xs[kk][m0 + 4]);
            float4 b0 = *reinterpret_cast<const float4*>(&Ws[kk][n0]);
            float4 b1 = *reinterpret_cast<const float4*>(&Ws[kk][n0 + 4]);
            const float af[8] = {a0.x, a0.y, a0.z, a0.w, a1.x, a1.y, a1.z, a1.w};
            const float bf[8] = {b0.x, b0.y, b0.z, b0.w, b1.x, b1.y, b1.z, b1.w};
#pragma unroll
            for (int i = 0; i < 8; ++i)
#pragma unroll
                for (int j = 0; j < 8; ++j)
                    accP[i][j] = fmaf(af[i], bf[j], accP[i][j]);
        }
        __syncthreads();

        // OpenBLAS SKYLAKEX K-split of 1024: 320 + 320 + 192 + 192
        const int kend = k0 + BK;
        if (kend == 320 || kend == 640 || kend == 832 || kend == 1024) {
#pragma unroll
            for (int i = 0; i < 8; ++i)
#pragma unroll
                for (int j = 0; j < 8; ++j) {
                    accT[i][j] = __fadd_rn(accT[i][j], accP[i][j]);
                    accP[i][j] = 0.0f;
                }
        }
    }

    // Epilogue: per-token top-2 over 64 experts (lower index wins ties).
    // Token m0+i's logits live in the 8 lanes sharing ty, 8 experts per lane.
#pragma unroll
    for (int i = 0; i < 8; ++i) {
        float v1 = accT[i][0]; int i1 = n0;
        float v2 = -INFINITY;  int i2 = 1 << 20;
#pragma unroll
        for (int j = 1; j < 8; ++j) {
            const float v = accT[i][j]; const int e = n0 + j;
            if (v > v1)      { v2 = v1; i2 = i1; v1 = v; i1 = e; }
            else if (v > v2) { v2 = v;  i2 = e; }
        }
        // merge across the 8-lane expert group (xor masks stay within tx bits)
#pragma unroll
        for (int m = 4; m >= 1; m >>= 1) {
            const float ov1 = __shfl_xor(v1, m);
            const int   oi1 = __shfl_xor(i1, m);
            const float ov2 = __shfl_xor(v2, m);
            const int   oi2 = __shfl_xor(i2, m);
            // tie-break: lower index wins on equal value
            const bool aw = (ov1 > v1) || (ov1 == v1 && oi1 < i1);
            const float nv1 = aw ? ov1 : v1; const int ni1 = aw ? oi1 : i1;
            const float c1v = aw ? v1  : ov1; const int c1i = aw ? i1  : oi1;
            const float c2v = aw ? ov2 : v2;  const int c2i = aw ? oi2 : i2;
            const bool bw = (c1v > c2v) || (c1v == c2v && c1i < c2i);
            v1 = nv1; i1 = ni1;
            v2 = bw ? c1v : c2v; i2 = bw ? c1i : c2i;
        }
        if (tx == 0) {
            const long t = t0 + m0 + i;
            const float e  = expf(v2 - v1);   // <= 1
            const float dn = 1.0f + e;
            out[t * 2 + 0] = (float)i1;       // indices stored as float values
            out[t * 2 + 1] = (float)i2;
            out[(long)T_TOKENS * 2 + t * 2 + 0] = 1.0f / dn;
            out[(long)T_TOKENS * 2 + t * 2 + 1] = e / dn;
        }
    }
}

extern "C" void kernel_launch(void* const* d_in, const int* in_sizes, int n_in,
                              void* d_out, int out_size, void* d_ws, size_t ws_size,
                              hipStream_t stream) {
    const float* x = (const float*)d_in[0];
    const float* W = (const float*)d_in[1];
    float* out = (float*)d_out;
    // d_in[2] is top_k (==2), fixed by the problem; k=2 is hardcoded.

    dim3 grid(T_TOKENS / BM);
    dim3 block(NTHREADS);
    topk_router_kernel<<<grid, block, 0, stream>>>(x, W, out);
}